// Round 1
// baseline (113.837 us; speedup 1.0000x reference)
//
#include <hip/hip_runtime.h>

// LocallyConnected2d: out[b,o,p,q] = sum_{i,kh,kw} x[b,i,2p+kh,2q+kw] * w[o,i,p,q,kh*3+kw]
// x: (8,32,64,64) f32, w: (1,32,32,31,31,9) f32, out: (8,32,31,31) f32

#define BB 8
#define CIN 32
#define COUT 32
#define HH 64
#define WW 64
#define HO 31
#define WO 31
#define NPOS (COUT * HO * WO)       // 30752 output positions (o,p,q)
#define XB_STRIDE (CIN * HH * WW)   // x batch stride in floats = 131072

__global__ __launch_bounds__(256) void lc2d_kernel(const float* __restrict__ x,
                                                   const float* __restrict__ wgt,
                                                   float* __restrict__ out) {
    const int tid = threadIdx.x;
    const int posInBlk = tid & 63;   // lanes = consecutive (o,p,q) -> coalesced weight
    const int chunk = tid >> 6;     // 0..3 -> i-range [chunk*8, chunk*8+8)
    const int pos = blockIdx.x * 64 + posInBlk;
    const bool valid = pos < NPOS;

    float acc[BB];
#pragma unroll
    for (int b = 0; b < BB; ++b) acc[b] = 0.f;

    if (valid) {
        const int o = pos / (HO * WO);
        const int rem = pos - o * (HO * WO);
        const int p = rem / WO;
        const int q = rem - p * WO;
        const int i0 = chunk * 8;

#pragma unroll
        for (int ii = 0; ii < 8; ++ii) {
            const int i = i0 + ii;
            // weight[o][i][p][q][0..8] contiguous
            const float* wp = wgt + ((size_t)((o * CIN + i) * (HO * WO) + rem)) * 9;
            float wv[9];
#pragma unroll
            for (int k = 0; k < 9; ++k) wv[k] = wp[k];

#pragma unroll
            for (int kh = 0; kh < 3; ++kh) {
                const float* xrow = x + ((size_t)i * HH + (p * 2 + kh)) * WW + q * 2;
#pragma unroll
                for (int b = 0; b < BB; ++b) {
                    const float* xb = xrow + (size_t)b * XB_STRIDE;
                    const float2 a = *reinterpret_cast<const float2*>(xb);       // cols 2q, 2q+1
                    const float2 c = *reinterpret_cast<const float2*>(xb + 2);   // cols 2q+2, 2q+3
                    acc[b] += wv[kh * 3 + 0] * a.x + wv[kh * 3 + 1] * a.y + wv[kh * 3 + 2] * c.x;
                }
            }
        }
    }

    // Reduce the 4 i-chunks per position through LDS.
    __shared__ float red[4][64][BB];
#pragma unroll
    for (int b = 0; b < BB; ++b) red[chunk][posInBlk][b] = acc[b];
    __syncthreads();

    if (tid < 64 && valid) {
        const int o = pos / (HO * WO);
        const int rem = pos - o * (HO * WO);
#pragma unroll
        for (int b = 0; b < BB; ++b) {
            const float s = red[0][tid][b] + red[1][tid][b] + red[2][tid][b] + red[3][tid][b];
            out[((size_t)b * COUT + o) * (HO * WO) + rem] = s;
        }
    }
}

extern "C" void kernel_launch(void* const* d_in, const int* in_sizes, int n_in,
                              void* d_out, int out_size, void* d_ws, size_t ws_size,
                              hipStream_t stream) {
    const float* x = (const float*)d_in[0];
    const float* w = (const float*)d_in[1];
    float* out = (float*)d_out;
    const int nblocks = (NPOS + 63) / 64;  // 481
    lc2d_kernel<<<dim3(nblocks), dim3(256), 0, stream>>>(x, w, out);
}

// Round 2
// 93.006 us; speedup vs baseline: 1.2240x; 1.2240x over previous
//
#include <hip/hip_runtime.h>

// LocallyConnected2d: out[b,o,p,q] = sum_{i,kh,kw} x[b,i,2p+kh,2q+kw] * w[o,i,p,q,kh*3+kw]
// x: (8,32,64,64) f32, w: (1,32,32,31,31,9) f32, out: (8,32,31,31) f32
//
// Decomposition: block = (p, og) with og = o-pair group (16 groups of 2 o).
//   512 threads = 16 i-chunks (ic) x 32 q-lanes (q=31 lane clamps to q=30, dup).
//   Thread computes acc[2 o][8 b] over i in {2*ic, 2*ic+1}.
//   Weight: each element read exactly ONCE device-wide (nontemporal b32 stream).
//   x: small (4.2 MB), L2-resident; loaded as aligned float2 pairs, shared
//   across the 2 o's in registers (16 FMA per x-load-pair).
//   i-reduction: LDS red[16][32][17] (stride-17 pad -> conflict-free).

#define CIN 32
#define COUT 32
#define HH 64
#define WW 64
#define HO 31
#define WO 31
#define XB 131072  // CIN*HH*WW floats, x batch stride

__global__ __launch_bounds__(512) void lc2d_kernel(const float* __restrict__ x,
                                                   const float* __restrict__ wgt,
                                                   float* __restrict__ out) {
    const int t = threadIdx.x;
    const int qlane = t & 31;                 // 0..31
    const int ic = t >> 5;                    // 0..15 (i-chunk of 2)
    const int p  = blockIdx.x >> 4;           // 0..30
    const int og = blockIdx.x & 15;           // 0..15
    const int q  = (qlane < 31) ? qlane : 30; // clamp duplicate lane (never stored)
    const int o0 = og * 2;

    float acc[2][8];
#pragma unroll
    for (int lo = 0; lo < 2; ++lo)
#pragma unroll
        for (int b = 0; b < 8; ++b) acc[lo][b] = 0.f;

    const int pq9 = (p * WO + q) * 9;

#pragma unroll
    for (int ii = 0; ii < 2; ++ii) {
        const int i = ic * 2 + ii;

        // weight[o0+lo][i][p][q][0..8] — contiguous 9 floats, read once device-wide
        float wv[2][9];
#pragma unroll
        for (int lo = 0; lo < 2; ++lo) {
            const float* wp = wgt + ((size_t)((o0 + lo) * CIN + i) * (HO * WO) + p * WO + q) * 9;
#pragma unroll
            for (int k = 0; k < 9; ++k) wv[lo][k] = __builtin_nontemporal_load(wp + k);
        }

#pragma unroll
        for (int kh = 0; kh < 3; ++kh) {
            const float* xr = x + ((size_t)i * HH + (2 * p + kh)) * WW + 2 * q;
            float xk[8][3];
#pragma unroll
            for (int b = 0; b < 8; ++b) {
                const float* xb = xr + (size_t)b * XB;
                const float2 a = *reinterpret_cast<const float2*>(xb);      // cols 2q,2q+1 (8B aligned)
                const float2 c = *reinterpret_cast<const float2*>(xb + 2);  // cols 2q+2,2q+3
                xk[b][0] = a.x; xk[b][1] = a.y; xk[b][2] = c.x;
            }
#pragma unroll
            for (int lo = 0; lo < 2; ++lo)
#pragma unroll
                for (int b = 0; b < 8; ++b)
#pragma unroll
                    for (int kw = 0; kw < 3; ++kw)
                        acc[lo][b] += wv[lo][kh * 3 + kw] * xk[b][kw];
        }
    }

    // Reduce 16 i-chunk partials per (q, o, b) through LDS.
    __shared__ float red[16][32][17];  // [ic][qlane][e], stride 17 -> all-32-bank spread
#pragma unroll
    for (int lo = 0; lo < 2; ++lo)
#pragma unroll
        for (int b = 0; b < 8; ++b)
            red[ic][qlane][lo * 8 + b] = acc[lo][b];
    __syncthreads();

    if (t < 496) {               // 16 e-groups x 31 q
        const int qq = t % 31;
        const int e  = t / 31;   // e = lo*8 + b
        float s = 0.f;
#pragma unroll
        for (int icc = 0; icc < 16; ++icc) s += red[icc][qq][e];
        const int lo = e >> 3, b = e & 7;
        out[(((size_t)b * COUT + o0 + lo) * HO + p) * WO + qq] = s;
    }
}

extern "C" void kernel_launch(void* const* d_in, const int* in_sizes, int n_in,
                              void* d_out, int out_size, void* d_ws, size_t ws_size,
                              hipStream_t stream) {
    const float* x = (const float*)d_in[0];
    const float* w = (const float*)d_in[1];
    float* out = (float*)d_out;
    lc2d_kernel<<<dim3(HO * 16), dim3(512), 0, stream>>>(x, w, out);  // 31 p x 16 og
}